// Round 13
// baseline (291.301 us; speedup 1.0000x reference)
//
#include <hip/hip_runtime.h>
#include <hip/hip_bf16.h>

#define IN_DIM 128
#define HID1 256
#define HID2 128

// ---------------------------------------------------------------- privatized histogram (src only,
// for deg_out/inv_o). dst degrees are computed inside scat_b.
#define HB_BINS 25000
#define HB_WORDS 12500
#define HB_CHUNKS 32
__global__ __launch_bounds__(256) void hist_src(const int* __restrict__ src,
                                                int E, int chunk_size,
                                                int* __restrict__ part, int N) {
    __shared__ int sm[HB_WORDS];
    const int base = blockIdx.y * HB_BINS;
    const int ebeg = blockIdx.x * chunk_size;
    const int eend = min(ebeg + chunk_size, E);
    for (int w = threadIdx.x; w < HB_WORDS; w += 256) sm[w] = 0;
    __syncthreads();
    for (int e = ebeg + threadIdx.x; e < eend; e += 256) {
        int v = src[e] - base;
        if ((unsigned)v < (unsigned)HB_BINS)
            atomicAdd(&sm[v >> 1], 1 << ((v & 1) * 16));
    }
    __syncthreads();
    const int nb = min(HB_BINS, N - base);
    int* dp = part + (size_t)blockIdx.x * N + base;
    for (int w = threadIdx.x; 2 * w < nb; w += 256) {
        int packed = sm[w];
        int b = 2 * w;
        dp[b] = packed & 0xffff;
        if (b + 1 < nb) dp[b + 1] = (packed >> 16) & 0xffff;
    }
}

__global__ __launch_bounds__(256) void hist_src_reduce(const int* __restrict__ part,
                                                       int N, float* __restrict__ inv_o) {
    int b = blockIdx.x * blockDim.x + threadIdx.x;
    if (b >= N) return;
    int d = 0;
#pragma unroll 4
    for (int k = 0; k < HB_CHUNKS; ++k) d += part[(size_t)k * N + b];
    inv_o[b] = rsqrtf((float)max(d, 1));
}

// ---------------------------------------------------------------- two-pass locality scatter
#define BK_SHIFT 8
#define NBUCK 196        // 256-node buckets
#define NCHUNK 256
// coarse per-(chunk,bucket) dst histogram; block 0 also zeroes hg_sum.
__global__ __launch_bounds__(256) void coarse_hist(const int* __restrict__ dst, int E,
                                                   int chunk_size, int* __restrict__ ccnt,
                                                   float* __restrict__ hg, int hg_n) {
    __shared__ int cnt[NBUCK];
    if (blockIdx.x == 0)
        for (int i = threadIdx.x; i < hg_n; i += 256) hg[i] = 0.f;
    for (int i = threadIdx.x; i < NBUCK; i += 256) cnt[i] = 0;
    __syncthreads();
    int ebeg = blockIdx.x * chunk_size, eend = min(ebeg + chunk_size, E);
    for (int e = ebeg + threadIdx.x; e < eend; e += 256)
        atomicAdd(&cnt[dst[e] >> BK_SHIFT], 1);
    __syncthreads();
    for (int i = threadIdx.x; i < NBUCK; i += 256) ccnt[blockIdx.x * NBUCK + i] = cnt[i];
}

// Per-bucket column scan over chunks: coffpre[c][b] = sum_{c'<c} ccnt[c'][b]; ctot[b] = column sum.
__global__ __launch_bounds__(NCHUNK) void coarse_col(const int* __restrict__ ccnt,
                                                     int* __restrict__ coffpre,
                                                     int* __restrict__ ctot) {
    __shared__ int sm[NCHUNK];
    const int b = blockIdx.x, t = threadIdx.x;
    int v = ccnt[t * NBUCK + b];
    sm[t] = v;
    __syncthreads();
#pragma unroll
    for (int off = 1; off < NCHUNK; off <<= 1) {
        int u = (t >= off) ? sm[t - off] : 0;
        __syncthreads();
        sm[t] += u;
        __syncthreads();
    }
    coffpre[t * NBUCK + b] = sm[t] - v;    // exclusive over chunks
    if (t == NCHUNK - 1) ctot[b] = sm[t];  // bucket total
}

// helper: exclusive scan of ctot[NBUCK] into bbase (inside 256-thread blocks)
__device__ __forceinline__ void scan_bbase(const int* __restrict__ ctot, int* sm, int* bbase) {
    const int t = threadIdx.x;
    int v = (t < NBUCK) ? ctot[t] : 0;
    sm[t] = v;
    __syncthreads();
#pragma unroll
    for (int off = 1; off < 256; off <<= 1) {
        int u = (t >= off) ? sm[t - off] : 0;
        __syncthreads();
        sm[t] += u;
        __syncthreads();
    }
    if (t < NBUCK) bbase[t] = sm[t] - v;
    __syncthreads();
}

// pass A: chunk-block scatters (src,dst) pairs into its private per-bucket segments.
__global__ __launch_bounds__(256) void scat_a(const int* __restrict__ src,
                                              const int* __restrict__ dst, int E,
                                              int chunk_size,
                                              const int* __restrict__ coffpre,
                                              const int* __restrict__ ctot,
                                              int2* __restrict__ pairs) {
    __shared__ int sm[256];
    __shared__ int bbase[NBUCK];
    __shared__ int lcur[NBUCK];
    scan_bbase(ctot, sm, bbase);
    for (int i = threadIdx.x; i < NBUCK; i += 256)
        lcur[i] = bbase[i] + coffpre[blockIdx.x * NBUCK + i];
    __syncthreads();
    int ebeg = blockIdx.x * chunk_size, eend = min(ebeg + chunk_size, E);
    for (int e = ebeg + threadIdx.x; e < eend; e += 256) {
        int d = dst[e];
        int p = atomicAdd(&lcur[d >> BK_SHIFT], 1);
        pairs[p] = make_int2(src[e], d);
    }
}

// pass B: bucket-block counts its nodes' in-degrees in LDS, emits row + inv_i, then places
// csr_src at final positions. All writes block-exclusive.
__global__ __launch_bounds__(256) void scat_b(const int2* __restrict__ pairs,
                                              const int* __restrict__ ctot, int N,
                                              int* __restrict__ row,
                                              float* __restrict__ inv_i,
                                              int* __restrict__ csr_src) {
    __shared__ int sm[256];
    __shared__ int bbase[NBUCK];
    __shared__ int cnt[1 << BK_SHIFT];
    __shared__ int cur[1 << BK_SHIFT];
    const int b = blockIdx.x, t = threadIdx.x;
    scan_bbase(ctot, sm, bbase);
    const int segBase = bbase[b];
    const int segEnd = segBase + ctot[b];
    const int nb0 = b << BK_SHIFT;
    const int nbn = min(256, N - nb0);   // nodes in this bucket
    cnt[t] = 0;
    __syncthreads();
    // pass 1: count in-degrees
    for (int j = segBase + t; j < segEnd; j += 256)
        atomicAdd(&cnt[pairs[j].y - nb0], 1);
    __syncthreads();
    // local exclusive scan of counts
    int v = cnt[t];
    sm[t] = v;
    __syncthreads();
#pragma unroll
    for (int off = 1; off < 256; off <<= 1) {
        int u = (t >= off) ? sm[t - off] : 0;
        __syncthreads();
        sm[t] += u;
        __syncthreads();
    }
    int excl = sm[t] - v;
    cur[t] = segBase + excl;
    if (t < nbn) {
        row[nb0 + t] = segBase + excl;
        inv_i[nb0 + t] = rsqrtf((float)max(v, 1));
        if (nb0 + t == N - 1) row[N] = segBase + excl + v;
    }
    __syncthreads();
    // pass 2: place (pairs re-read is L2-hot)
    for (int j = segBase + t; j < segEnd; j += 256) {
        int2 pr = pairs[j];
        int p = atomicAdd(&cur[pr.y - nb0], 1);
        csr_src[p] = pr.x;
    }
}

// ---------------------------------------------------------------- one-shot conversions:
// x_bf = bf16(x * inv_o[row]) plus both weight transposes ([K][N] fp32 -> [N][K] bf16).
__global__ void cvt_all(const float* __restrict__ x, const float* __restrict__ inv_o,
                        __hip_bfloat16* __restrict__ x_bf, int n4x,
                        const float* __restrict__ W1, __hip_bfloat16* __restrict__ W1t,
                        const float* __restrict__ W2, __hip_bfloat16* __restrict__ W2t) {
    const int S1 = IN_DIM * HID1;
    const int S2 = HID1 * HID2;
    int i = blockIdx.x * blockDim.x + threadIdx.x;
    if (i < n4x) {
        float s = inv_o[i >> 5];
        float4 v = reinterpret_cast<const float4*>(x)[i];
        __hip_bfloat16 b0 = __float2bfloat16(v.x * s);
        __hip_bfloat16 b1 = __float2bfloat16(v.y * s);
        __hip_bfloat16 b2 = __float2bfloat16(v.z * s);
        __hip_bfloat16 b3 = __float2bfloat16(v.w * s);
        ushort4 o = make_ushort4(*(unsigned short*)&b0, *(unsigned short*)&b1,
                                 *(unsigned short*)&b2, *(unsigned short*)&b3);
        reinterpret_cast<ushort4*>(x_bf)[i] = o;
    } else {
        int idx = i - n4x;
        if (idx < S1) {
            int k = idx / HID1, n = idx - k * HID1;
            W1t[n * IN_DIM + k] = __float2bfloat16(W1[idx]);
        } else if (idx < S1 + S2) {
            int j = idx - S1;
            int k = j / HID2, n = j - k * HID2;
            W2t[n * HID1 + k] = __float2bfloat16(W2[j]);
        }
    }
}

// ---------------------------------------------------------------- CSR SpMM, bf16 feat, F=128.
__device__ __forceinline__ void bf2_unpack(unsigned int p, float& lo, float& hi) {
    lo = __uint_as_float(p << 16);
    hi = __uint_as_float(p & 0xffff0000u);
}

__global__ __launch_bounds__(256) void spmm_kernel(const __hip_bfloat16* __restrict__ feat,
                                                   const int* __restrict__ row,
                                                   const int* __restrict__ csr_src,
                                                   __hip_bfloat16* __restrict__ out_bf, int N) {
    const int node = blockIdx.x * 4 + (threadIdx.x >> 6);
    if (node >= N) return;
    const int lane = threadIdx.x & 63;
    const unsigned int* fp = (const unsigned int*)feat;
    const int beg = row[node];
    const int end = row[node + 1];
    float a0 = 0.f, a1 = 0.f;
    int j = beg;
    for (; j + 8 <= end; j += 8) {
        int s0 = csr_src[j],     s1 = csr_src[j + 1], s2 = csr_src[j + 2], s3 = csr_src[j + 3];
        int s4 = csr_src[j + 4], s5 = csr_src[j + 5], s6 = csr_src[j + 6], s7 = csr_src[j + 7];
        unsigned int p0 = fp[(size_t)s0 * 64 + lane];
        unsigned int p1 = fp[(size_t)s1 * 64 + lane];
        unsigned int p2 = fp[(size_t)s2 * 64 + lane];
        unsigned int p3 = fp[(size_t)s3 * 64 + lane];
        unsigned int p4 = fp[(size_t)s4 * 64 + lane];
        unsigned int p5 = fp[(size_t)s5 * 64 + lane];
        unsigned int p6 = fp[(size_t)s6 * 64 + lane];
        unsigned int p7 = fp[(size_t)s7 * 64 + lane];
        float lo, hi;
        bf2_unpack(p0, lo, hi); a0 += lo; a1 += hi;
        bf2_unpack(p1, lo, hi); a0 += lo; a1 += hi;
        bf2_unpack(p2, lo, hi); a0 += lo; a1 += hi;
        bf2_unpack(p3, lo, hi); a0 += lo; a1 += hi;
        bf2_unpack(p4, lo, hi); a0 += lo; a1 += hi;
        bf2_unpack(p5, lo, hi); a0 += lo; a1 += hi;
        bf2_unpack(p6, lo, hi); a0 += lo; a1 += hi;
        bf2_unpack(p7, lo, hi); a0 += lo; a1 += hi;
    }
    for (; j + 4 <= end; j += 4) {
        int s0 = csr_src[j], s1 = csr_src[j + 1], s2 = csr_src[j + 2], s3 = csr_src[j + 3];
        unsigned int p0 = fp[(size_t)s0 * 64 + lane];
        unsigned int p1 = fp[(size_t)s1 * 64 + lane];
        unsigned int p2 = fp[(size_t)s2 * 64 + lane];
        unsigned int p3 = fp[(size_t)s3 * 64 + lane];
        float lo, hi;
        bf2_unpack(p0, lo, hi); a0 += lo; a1 += hi;
        bf2_unpack(p1, lo, hi); a0 += lo; a1 += hi;
        bf2_unpack(p2, lo, hi); a0 += lo; a1 += hi;
        bf2_unpack(p3, lo, hi); a0 += lo; a1 += hi;
    }
    for (; j < end; ++j) {
        unsigned int p0 = fp[(size_t)csr_src[j] * 64 + lane];
        float lo, hi;
        bf2_unpack(p0, lo, hi); a0 += lo; a1 += hi;
    }
    __hip_bfloat16 b0 = __float2bfloat16(a0);
    __hip_bfloat16 b1 = __float2bfloat16(a1);
    unsigned int packed = (unsigned int)(*(unsigned short*)&b0) |
                          ((unsigned int)(*(unsigned short*)&b1) << 16);
    ((unsigned int*)out_bf)[(size_t)node * 64 + lane] = packed;
}

// ---------------------------------------------------------------- fused SpMM + pool (layer 2).
// R11-measured config: SP_NODES 8, unroll 4 (46 µs; R12's SP4+unroll8 regressed to 51.5).
#define SP_NODES 8
__global__ __launch_bounds__(256) void spmm_pool_kernel(const __hip_bfloat16* __restrict__ feat,
                                                        const int* __restrict__ row,
                                                        const int* __restrict__ csr_src,
                                                        const float* __restrict__ inv_i,
                                                        const float* __restrict__ b2,
                                                        const int* __restrict__ graph_id,
                                                        int N, float* __restrict__ hg_sum) {
    const int wave = blockIdx.x * 4 + (threadIdx.x >> 6);
    const int lane = threadIdx.x & 63;
    const int n0 = wave * SP_NODES;
    if (n0 >= N) return;
    const int n1 = min(n0 + SP_NODES, N);
    const unsigned int* fp = (const unsigned int*)feat;
    const float bias0 = b2[2 * lane];
    const float bias1 = b2[2 * lane + 1];
    int g = graph_id[n0];
    float p0s = 0.f, p1s = 0.f;
    for (int node = n0; node < n1; ++node) {
        int gi = graph_id[node];
        if (gi != g) {
            atomicAdd(&hg_sum[g * HID2 + 2 * lane], p0s);
            atomicAdd(&hg_sum[g * HID2 + 2 * lane + 1], p1s);
            p0s = p1s = 0.f;
            g = gi;
        }
        const int beg = row[node];
        const int end = row[node + 1];
        float a0 = 0.f, a1 = 0.f;
        int j = beg;
        for (; j + 4 <= end; j += 4) {
            int s0 = csr_src[j], s1 = csr_src[j + 1], s2 = csr_src[j + 2], s3 = csr_src[j + 3];
            unsigned int q0 = fp[(size_t)s0 * 64 + lane];
            unsigned int q1 = fp[(size_t)s1 * 64 + lane];
            unsigned int q2 = fp[(size_t)s2 * 64 + lane];
            unsigned int q3 = fp[(size_t)s3 * 64 + lane];
            float lo, hi;
            bf2_unpack(q0, lo, hi); a0 += lo; a1 += hi;
            bf2_unpack(q1, lo, hi); a0 += lo; a1 += hi;
            bf2_unpack(q2, lo, hi); a0 += lo; a1 += hi;
            bf2_unpack(q3, lo, hi); a0 += lo; a1 += hi;
        }
        for (; j < end; ++j) {
            unsigned int q0 = fp[(size_t)csr_src[j] * 64 + lane];
            float lo, hi;
            bf2_unpack(q0, lo, hi); a0 += lo; a1 += hi;
        }
        float ii = inv_i[node];
        p0s += fmaxf(a0 * ii + bias0, 0.f);
        p1s += fmaxf(a1 * ii + bias1, 0.f);
    }
    atomicAdd(&hg_sum[g * HID2 + 2 * lane], p0s);
    atomicAdd(&hg_sum[g * HID2 + 2 * lane + 1], p1s);
}

// ---------------------------------------------------------------- MFMA bf16 GEMM
#define GBM 128
#define GBN 128
#define GBK 32
#define LPAD 40
typedef __attribute__((ext_vector_type(4))) float floatx4;
typedef __attribute__((ext_vector_type(8))) short shortx8;

__global__ __launch_bounds__(256) void mfma_gemm_kernel(const __hip_bfloat16* __restrict__ A,
                                                        const __hip_bfloat16* __restrict__ Bt,
                                                        __hip_bfloat16* __restrict__ C,
                                                        const float* __restrict__ scaleR,
                                                        const float* __restrict__ bias,
                                                        const float* __restrict__ scaleO,
                                                        int M, int Nn, int K, int doRelu) {
    __shared__ __align__(16) __hip_bfloat16 As[GBM * LPAD];
    __shared__ __align__(16) __hip_bfloat16 Bs[GBN * LPAD];
    const int tid = threadIdx.x;
    const int bm = blockIdx.x * GBM;
    const int bn = blockIdx.y * GBN;
    const int wid = tid >> 6;
    const int lane = tid & 63;
    const int wm = (wid & 1) * 64;
    const int wn = (wid >> 1) * 64;
    const int lrow = lane & 15;
    const int quad = lane >> 4;

    floatx4 acc[4][4] = {};

    for (int k0 = 0; k0 < K; k0 += GBK) {
#pragma unroll
        for (int it = 0; it < 2; ++it) {
            int slot = tid + (it << 8);
            int r = slot >> 2;
            int c = (slot & 3) << 3;
            int gr = bm + r;
            float4 v = make_float4(0.f, 0.f, 0.f, 0.f);
            if (gr < M) v = *reinterpret_cast<const float4*>(A + (size_t)gr * K + k0 + c);
            *reinterpret_cast<float4*>(&As[r * LPAD + c]) = v;
        }
#pragma unroll
        for (int it = 0; it < 2; ++it) {
            int slot = tid + (it << 8);
            int r = slot >> 2;
            int c = (slot & 3) << 3;
            float4 v = *reinterpret_cast<const float4*>(Bt + (size_t)(bn + r) * K + k0 + c);
            *reinterpret_cast<float4*>(&Bs[r * LPAD + c]) = v;
        }
        __syncthreads();

        shortx8 af[4], bf[4];
#pragma unroll
        for (int i = 0; i < 4; ++i)
            af[i] = *reinterpret_cast<const shortx8*>(&As[(wm + i * 16 + lrow) * LPAD + quad * 8]);
#pragma unroll
        for (int i = 0; i < 4; ++i)
            bf[i] = *reinterpret_cast<const shortx8*>(&Bs[(wn + i * 16 + lrow) * LPAD + quad * 8]);
#pragma unroll
        for (int im = 0; im < 4; ++im)
#pragma unroll
            for (int in = 0; in < 4; ++in)
                acc[im][in] = __builtin_amdgcn_mfma_f32_16x16x32_bf16(af[im], bf[in], acc[im][in], 0, 0, 0);
        __syncthreads();
    }

    float bv[4];
#pragma unroll
    for (int in = 0; in < 4; ++in)
        bv[in] = bias ? bias[bn + wn + in * 16 + lrow] : 0.f;

#pragma unroll
    for (int im = 0; im < 4; ++im) {
#pragma unroll
        for (int reg = 0; reg < 4; ++reg) {
            int r = bm + wm + im * 16 + quad * 4 + reg;
            if (r >= M) continue;
            float sR = scaleR ? scaleR[r] : 1.f;
            float sO = scaleO ? scaleO[r] : 1.f;
#pragma unroll
            for (int in = 0; in < 4; ++in) {
                int c = bn + wn + in * 16 + lrow;
                float v = acc[im][in][reg] * sR + bv[in];
                if (doRelu) v = fmaxf(v, 0.f);
                v *= sO;
                C[(size_t)r * Nn + c] = __float2bfloat16(v);
            }
        }
    }
}

// ---------------------------------------------------------------- tiny 3-layer MLP, block/graph
__device__ __forceinline__ int lower_bound_i(const int* a, int n, int key) {
    int lo = 0, hi = n;
    while (lo < hi) {
        int mid = (lo + hi) >> 1;
        if (a[mid] < key) lo = mid + 1; else hi = mid;
    }
    return lo;
}

__global__ __launch_bounds__(64) void mlp_kernel(const float* __restrict__ hg_sum,
                                                 const int* __restrict__ graph_id, int n,
                                                 const float* __restrict__ Wc1, const float* __restrict__ bc1,
                                                 const float* __restrict__ Wc2, const float* __restrict__ bc2,
                                                 const float* __restrict__ Wc3, const float* __restrict__ bc3,
                                                 float* __restrict__ out) {
    const int g = blockIdx.x;
    const int t = threadIdx.x;
    __shared__ float h[HID2];
    __shared__ float t1[12];
    __shared__ float t2[12];
    __shared__ float s_inv_cnt;
    if (t == 0) {
        int beg = lower_bound_i(graph_id, n, g);
        int end = lower_bound_i(graph_id, n, g + 1);
        int c = end - beg;
        s_inv_cnt = 1.0f / (float)max(c, 1);
    }
    __syncthreads();
    const float ic = s_inv_cnt;
    for (int i = t; i < HID2; i += 64) h[i] = hg_sum[g * HID2 + i] * ic;
    __syncthreads();
    if (t < 12) {
        float a = bc1[t];
        for (int k = 0; k < HID2; ++k) a += h[k] * Wc1[k * 12 + t];
        t1[t] = a;
    }
    __syncthreads();
    if (t < 12) {
        float a = bc2[t];
        for (int k = 0; k < 12; ++k) a += t1[k] * Wc2[k * 12 + t];
        t2[t] = a;
    }
    __syncthreads();
    if (t < 10) {
        float a = bc3[t];
        for (int k = 0; k < 12; ++k) a += t2[k] * Wc3[k * 10 + t];
        out[g * 10 + t] = a;
    }
}

// ================================================================ launch
extern "C" void kernel_launch(void* const* d_in, const int* in_sizes, int n_in,
                              void* d_out, int out_size, void* d_ws, size_t ws_size,
                              hipStream_t stream) {
    const float* x        = (const float*)d_in[0];
    const int*   src      = (const int*)d_in[1];
    const int*   dst      = (const int*)d_in[2];
    const int*   graph_id = (const int*)d_in[3];
    const float* W1       = (const float*)d_in[4];
    const float* b1       = (const float*)d_in[5];
    const float* W2       = (const float*)d_in[6];
    const float* b2       = (const float*)d_in[7];
    const float* Wc1      = (const float*)d_in[8];
    const float* bc1      = (const float*)d_in[9];
    const float* Wc2      = (const float*)d_in[10];
    const float* bc2      = (const float*)d_in[11];
    const float* Wc3      = (const float*)d_in[12];
    const float* bc3      = (const float*)d_in[13];
    float* out = (float*)d_out;

    const int N = in_sizes[0] / IN_DIM;   // 50000
    const int E = in_sizes[1];            // 800000
    const int G = out_size / 10;          // 64

    char* ws = (char*)d_ws;
    size_t off = 0;
    auto alloc = [&](size_t bytes) -> char* {
        char* p = ws + off;
        off = (off + bytes + 255) & ~(size_t)255;
        return p;
    };
    float* inv_i   = (float*)alloc((size_t)N * 4);
    float* inv_o   = (float*)alloc((size_t)N * 4);
    int*   row     = (int*)alloc((size_t)(N + 1) * 4);
    int*   ccnt    = (int*)alloc((size_t)NCHUNK * NBUCK * 4);
    int*   coffpre = (int*)alloc((size_t)NCHUNK * NBUCK * 4);
    int*   ctot    = (int*)alloc((size_t)NBUCK * 4);
    int2*  pairs   = (int2*)alloc((size_t)E * 8);
    int*   csr_src = (int*)alloc((size_t)E * 4);
    float* hg      = (float*)alloc((size_t)G * HID2 * 4);
    __hip_bfloat16* x_bf    = (__hip_bfloat16*)alloc((size_t)N * IN_DIM * 2);
    __hip_bfloat16* W1t     = (__hip_bfloat16*)alloc((size_t)IN_DIM * HID1 * 2);
    __hip_bfloat16* W2t     = (__hip_bfloat16*)alloc((size_t)HID1 * HID2 * 2);
    __hip_bfloat16* agg1_bf = (__hip_bfloat16*)alloc((size_t)N * IN_DIM * 2);
    __hip_bfloat16* h1_bf   = (__hip_bfloat16*)alloc((size_t)N * HID1 * 2);
    __hip_bfloat16* xw2_bf  = (__hip_bfloat16*)alloc((size_t)N * HID2 * 2);

    // src-histogram partials alias h1_bf (consumed by hist_src_reduce before gemm1 writes h1_bf)
    int* part = (int*)h1_bf;   // HB_CHUNKS * N ints = 6.4 MB <= 25.6 MB

    // deg_out -> inv_o (privatized, no global atomics)
    const int hchunk = (E + HB_CHUNKS - 1) / HB_CHUNKS;   // 25000 <= 65535 (16-bit counters)
    const int n_ranges = (N + HB_BINS - 1) / HB_BINS;
    hist_src<<<dim3(HB_CHUNKS, n_ranges), 256, 0, stream>>>(src, E, hchunk, part, N);
    hist_src_reduce<<<(N + 255) / 256, 256, 0, stream>>>(part, N, inv_o);

    // CSR build: coarse dst hist (+hg zero), per-bucket column scans, two-pass scatter.
    const int schunk = (E + NCHUNK - 1) / NCHUNK;
    coarse_hist<<<NCHUNK, 256, 0, stream>>>(dst, E, schunk, ccnt, hg, G * HID2);
    coarse_col<<<NBUCK, NCHUNK, 0, stream>>>(ccnt, coffpre, ctot);
    scat_a<<<NCHUNK, 256, 0, stream>>>(src, dst, E, schunk, coffpre, ctot, pairs);
    scat_b<<<NBUCK, 256, 0, stream>>>(pairs, ctot, N, row, inv_i, csr_src);

    // conversions: x*inv_o -> bf16, both weight transposes, one launch
    const int n4x = N * IN_DIM / 4;
    cvt_all<<<(n4x + IN_DIM * HID1 + HID1 * HID2 + 255) / 256, 256, 0, stream>>>(
        x, inv_o, x_bf, n4x, W1, W1t, W2, W2t);

    // Layer 1: agg1 = A * (x*inv_o); h1 = relu(inv_i*(agg1@W1) + b1) * inv_o
    spmm_kernel<<<(N + 3) / 4, 256, 0, stream>>>(x_bf, row, csr_src, agg1_bf, N);
    mfma_gemm_kernel<<<dim3((N + GBM - 1) / GBM, HID1 / GBN), 256, 0, stream>>>(
        agg1_bf, W1t, h1_bf, inv_i, b1, inv_o, N, HID1, IN_DIM, 1);

    // Layer 2: xw2 = h1 @ W2 (h1 carries inv_o); fused spmm+pool
    mfma_gemm_kernel<<<dim3((N + GBM - 1) / GBM, HID2 / GBN), 256, 0, stream>>>(
        h1_bf, W2t, xw2_bf, nullptr, nullptr, nullptr, N, HID2, HID1, 0);
    const int npw = (N + SP_NODES - 1) / SP_NODES;           // waves
    spmm_pool_kernel<<<(npw + 3) / 4, 256, 0, stream>>>(xw2_bf, row, csr_src, inv_i, b2,
                                                        graph_id, N, hg);

    // MLP (fused mean-divide)
    mlp_kernel<<<G, 64, 0, stream>>>(hg, graph_id, N, Wc1, bc1, Wc2, bc2, Wc3, bc3, out);
}

// Round 14
// 274.033 us; speedup vs baseline: 1.0630x; 1.0630x over previous
//
#include <hip/hip_runtime.h>
#include <hip/hip_bf16.h>

#define IN_DIM 128
#define HID1 256
#define HID2 128

// ---------------------------------------------------------------- privatized histogram (src only,
// for deg_out/inv_o). dst degrees are computed inside scat_b.
// 256 blocks (64 chunks x 4 ranges), 25 KB LDS each -> high occupancy (R13's 64-block config
// was parallelism-starved at 49 us).
#define HB_BINS 12500
#define HB_WORDS 6250
#define HB_CHUNKS 64
__global__ __launch_bounds__(256) void hist_src(const int* __restrict__ src,
                                                int E, int chunk_size,
                                                int* __restrict__ part, int N) {
    __shared__ int sm[HB_WORDS];
    const int base = blockIdx.y * HB_BINS;
    const int ebeg = blockIdx.x * chunk_size;
    const int eend = min(ebeg + chunk_size, E);
    for (int w = threadIdx.x; w < HB_WORDS; w += 256) sm[w] = 0;
    __syncthreads();
    for (int e = ebeg + threadIdx.x; e < eend; e += 256) {
        int v = src[e] - base;
        if ((unsigned)v < (unsigned)HB_BINS)
            atomicAdd(&sm[v >> 1], 1 << ((v & 1) * 16));
    }
    __syncthreads();
    const int nb = min(HB_BINS, N - base);
    int* dp = part + (size_t)blockIdx.x * N + base;
    for (int w = threadIdx.x; 2 * w < nb; w += 256) {
        int packed = sm[w];
        int b = 2 * w;
        dp[b] = packed & 0xffff;
        if (b + 1 < nb) dp[b + 1] = (packed >> 16) & 0xffff;
    }
}

__global__ __launch_bounds__(256) void hist_src_reduce(const int* __restrict__ part,
                                                       int N, float* __restrict__ inv_o) {
    int b = blockIdx.x * blockDim.x + threadIdx.x;
    if (b >= N) return;
    int d = 0;
#pragma unroll 4
    for (int k = 0; k < HB_CHUNKS; ++k) d += part[(size_t)k * N + b];
    inv_o[b] = rsqrtf((float)max(d, 1));
}

// ---------------------------------------------------------------- two-pass locality scatter
#define BK_SHIFT 8
#define NBUCK 196        // 256-node buckets
#define NCHUNK 256
// coarse per-(chunk,bucket) dst histogram; block 0 also zeroes hg_sum.
__global__ __launch_bounds__(256) void coarse_hist(const int* __restrict__ dst, int E,
                                                   int chunk_size, int* __restrict__ ccnt,
                                                   float* __restrict__ hg, int hg_n) {
    __shared__ int cnt[NBUCK];
    if (blockIdx.x == 0)
        for (int i = threadIdx.x; i < hg_n; i += 256) hg[i] = 0.f;
    for (int i = threadIdx.x; i < NBUCK; i += 256) cnt[i] = 0;
    __syncthreads();
    int ebeg = blockIdx.x * chunk_size, eend = min(ebeg + chunk_size, E);
    for (int e = ebeg + threadIdx.x; e < eend; e += 256)
        atomicAdd(&cnt[dst[e] >> BK_SHIFT], 1);
    __syncthreads();
    for (int i = threadIdx.x; i < NBUCK; i += 256) ccnt[blockIdx.x * NBUCK + i] = cnt[i];
}

// Per-bucket column scan over chunks: coffpre[c][b] = sum_{c'<c} ccnt[c'][b]; ctot[b] = column sum.
__global__ __launch_bounds__(NCHUNK) void coarse_col(const int* __restrict__ ccnt,
                                                     int* __restrict__ coffpre,
                                                     int* __restrict__ ctot) {
    __shared__ int sm[NCHUNK];
    const int b = blockIdx.x, t = threadIdx.x;
    int v = ccnt[t * NBUCK + b];
    sm[t] = v;
    __syncthreads();
#pragma unroll
    for (int off = 1; off < NCHUNK; off <<= 1) {
        int u = (t >= off) ? sm[t - off] : 0;
        __syncthreads();
        sm[t] += u;
        __syncthreads();
    }
    coffpre[t * NBUCK + b] = sm[t] - v;    // exclusive over chunks
    if (t == NCHUNK - 1) ctot[b] = sm[t];  // bucket total
}

// helper: exclusive scan of ctot[NBUCK] into bbase (inside 256-thread blocks)
__device__ __forceinline__ void scan_bbase(const int* __restrict__ ctot, int* sm, int* bbase) {
    const int t = threadIdx.x;
    int v = (t < NBUCK) ? ctot[t] : 0;
    sm[t] = v;
    __syncthreads();
#pragma unroll
    for (int off = 1; off < 256; off <<= 1) {
        int u = (t >= off) ? sm[t - off] : 0;
        __syncthreads();
        sm[t] += u;
        __syncthreads();
    }
    if (t < NBUCK) bbase[t] = sm[t] - v;
    __syncthreads();
}

// pass A: chunk-block scatters (src,dst) pairs into its private per-bucket segments.
__global__ __launch_bounds__(256) void scat_a(const int* __restrict__ src,
                                              const int* __restrict__ dst, int E,
                                              int chunk_size,
                                              const int* __restrict__ coffpre,
                                              const int* __restrict__ ctot,
                                              int2* __restrict__ pairs) {
    __shared__ int sm[256];
    __shared__ int bbase[NBUCK];
    __shared__ int lcur[NBUCK];
    scan_bbase(ctot, sm, bbase);
    for (int i = threadIdx.x; i < NBUCK; i += 256)
        lcur[i] = bbase[i] + coffpre[blockIdx.x * NBUCK + i];
    __syncthreads();
    int ebeg = blockIdx.x * chunk_size, eend = min(ebeg + chunk_size, E);
    for (int e = ebeg + threadIdx.x; e < eend; e += 256) {
        int d = dst[e];
        int p = atomicAdd(&lcur[d >> BK_SHIFT], 1);
        pairs[p] = make_int2(src[e], d);
    }
}

// pass B: bucket-block counts its nodes' in-degrees in LDS, emits row + inv_i, then places
// csr_src at final positions. All writes block-exclusive.
__global__ __launch_bounds__(256) void scat_b(const int2* __restrict__ pairs,
                                              const int* __restrict__ ctot, int N,
                                              int* __restrict__ row,
                                              float* __restrict__ inv_i,
                                              int* __restrict__ csr_src) {
    __shared__ int sm[256];
    __shared__ int bbase[NBUCK];
    __shared__ int cnt[1 << BK_SHIFT];
    __shared__ int cur[1 << BK_SHIFT];
    const int b = blockIdx.x, t = threadIdx.x;
    scan_bbase(ctot, sm, bbase);
    const int segBase = bbase[b];
    const int segEnd = segBase + ctot[b];
    const int nb0 = b << BK_SHIFT;
    const int nbn = min(256, N - nb0);   // nodes in this bucket
    cnt[t] = 0;
    __syncthreads();
    // pass 1: count in-degrees
    for (int j = segBase + t; j < segEnd; j += 256)
        atomicAdd(&cnt[pairs[j].y - nb0], 1);
    __syncthreads();
    // local exclusive scan of counts
    int v = cnt[t];
    sm[t] = v;
    __syncthreads();
#pragma unroll
    for (int off = 1; off < 256; off <<= 1) {
        int u = (t >= off) ? sm[t - off] : 0;
        __syncthreads();
        sm[t] += u;
        __syncthreads();
    }
    int excl = sm[t] - v;
    cur[t] = segBase + excl;
    if (t < nbn) {
        row[nb0 + t] = segBase + excl;
        inv_i[nb0 + t] = rsqrtf((float)max(v, 1));
        if (nb0 + t == N - 1) row[N] = segBase + excl + v;
    }
    __syncthreads();
    // pass 2: place (pairs re-read is L2-hot)
    for (int j = segBase + t; j < segEnd; j += 256) {
        int2 pr = pairs[j];
        int p = atomicAdd(&cur[pr.y - nb0], 1);
        csr_src[p] = pr.x;
    }
}

// ---------------------------------------------------------------- one-shot conversions:
// x_bf = bf16(x * inv_o[row]) plus both weight transposes ([K][N] fp32 -> [N][K] bf16).
__global__ void cvt_all(const float* __restrict__ x, const float* __restrict__ inv_o,
                        __hip_bfloat16* __restrict__ x_bf, int n4x,
                        const float* __restrict__ W1, __hip_bfloat16* __restrict__ W1t,
                        const float* __restrict__ W2, __hip_bfloat16* __restrict__ W2t) {
    const int S1 = IN_DIM * HID1;
    const int S2 = HID1 * HID2;
    int i = blockIdx.x * blockDim.x + threadIdx.x;
    if (i < n4x) {
        float s = inv_o[i >> 5];
        float4 v = reinterpret_cast<const float4*>(x)[i];
        __hip_bfloat16 b0 = __float2bfloat16(v.x * s);
        __hip_bfloat16 b1 = __float2bfloat16(v.y * s);
        __hip_bfloat16 b2 = __float2bfloat16(v.z * s);
        __hip_bfloat16 b3 = __float2bfloat16(v.w * s);
        ushort4 o = make_ushort4(*(unsigned short*)&b0, *(unsigned short*)&b1,
                                 *(unsigned short*)&b2, *(unsigned short*)&b3);
        reinterpret_cast<ushort4*>(x_bf)[i] = o;
    } else {
        int idx = i - n4x;
        if (idx < S1) {
            int k = idx / HID1, n = idx - k * HID1;
            W1t[n * IN_DIM + k] = __float2bfloat16(W1[idx]);
        } else if (idx < S1 + S2) {
            int j = idx - S1;
            int k = j / HID2, n = j - k * HID2;
            W2t[n * HID1 + k] = __float2bfloat16(W2[j]);
        }
    }
}

// ---------------------------------------------------------------- CSR SpMM, bf16 feat, F=128.
__device__ __forceinline__ void bf2_unpack(unsigned int p, float& lo, float& hi) {
    lo = __uint_as_float(p << 16);
    hi = __uint_as_float(p & 0xffff0000u);
}

__global__ __launch_bounds__(256) void spmm_kernel(const __hip_bfloat16* __restrict__ feat,
                                                   const int* __restrict__ row,
                                                   const int* __restrict__ csr_src,
                                                   __hip_bfloat16* __restrict__ out_bf, int N) {
    const int node = blockIdx.x * 4 + (threadIdx.x >> 6);
    if (node >= N) return;
    const int lane = threadIdx.x & 63;
    const unsigned int* fp = (const unsigned int*)feat;
    const int beg = row[node];
    const int end = row[node + 1];
    float a0 = 0.f, a1 = 0.f;
    int j = beg;
    for (; j + 8 <= end; j += 8) {
        int s0 = csr_src[j],     s1 = csr_src[j + 1], s2 = csr_src[j + 2], s3 = csr_src[j + 3];
        int s4 = csr_src[j + 4], s5 = csr_src[j + 5], s6 = csr_src[j + 6], s7 = csr_src[j + 7];
        unsigned int p0 = fp[(size_t)s0 * 64 + lane];
        unsigned int p1 = fp[(size_t)s1 * 64 + lane];
        unsigned int p2 = fp[(size_t)s2 * 64 + lane];
        unsigned int p3 = fp[(size_t)s3 * 64 + lane];
        unsigned int p4 = fp[(size_t)s4 * 64 + lane];
        unsigned int p5 = fp[(size_t)s5 * 64 + lane];
        unsigned int p6 = fp[(size_t)s6 * 64 + lane];
        unsigned int p7 = fp[(size_t)s7 * 64 + lane];
        float lo, hi;
        bf2_unpack(p0, lo, hi); a0 += lo; a1 += hi;
        bf2_unpack(p1, lo, hi); a0 += lo; a1 += hi;
        bf2_unpack(p2, lo, hi); a0 += lo; a1 += hi;
        bf2_unpack(p3, lo, hi); a0 += lo; a1 += hi;
        bf2_unpack(p4, lo, hi); a0 += lo; a1 += hi;
        bf2_unpack(p5, lo, hi); a0 += lo; a1 += hi;
        bf2_unpack(p6, lo, hi); a0 += lo; a1 += hi;
        bf2_unpack(p7, lo, hi); a0 += lo; a1 += hi;
    }
    for (; j + 4 <= end; j += 4) {
        int s0 = csr_src[j], s1 = csr_src[j + 1], s2 = csr_src[j + 2], s3 = csr_src[j + 3];
        unsigned int p0 = fp[(size_t)s0 * 64 + lane];
        unsigned int p1 = fp[(size_t)s1 * 64 + lane];
        unsigned int p2 = fp[(size_t)s2 * 64 + lane];
        unsigned int p3 = fp[(size_t)s3 * 64 + lane];
        float lo, hi;
        bf2_unpack(p0, lo, hi); a0 += lo; a1 += hi;
        bf2_unpack(p1, lo, hi); a0 += lo; a1 += hi;
        bf2_unpack(p2, lo, hi); a0 += lo; a1 += hi;
        bf2_unpack(p3, lo, hi); a0 += lo; a1 += hi;
    }
    for (; j < end; ++j) {
        unsigned int p0 = fp[(size_t)csr_src[j] * 64 + lane];
        float lo, hi;
        bf2_unpack(p0, lo, hi); a0 += lo; a1 += hi;
    }
    __hip_bfloat16 b0 = __float2bfloat16(a0);
    __hip_bfloat16 b1 = __float2bfloat16(a1);
    unsigned int packed = (unsigned int)(*(unsigned short*)&b0) |
                          ((unsigned int)(*(unsigned short*)&b1) << 16);
    ((unsigned int*)out_bf)[(size_t)node * 64 + lane] = packed;
}

// ---------------------------------------------------------------- fused SpMM + pool (layer 2).
// Best-known config: SP_NODES 8, unroll 4 (47 us measured R13).
#define SP_NODES 8
__global__ __launch_bounds__(256) void spmm_pool_kernel(const __hip_bfloat16* __restrict__ feat,
                                                        const int* __restrict__ row,
                                                        const int* __restrict__ csr_src,
                                                        const float* __restrict__ inv_i,
                                                        const float* __restrict__ b2,
                                                        const int* __restrict__ graph_id,
                                                        int N, float* __restrict__ hg_sum) {
    const int wave = blockIdx.x * 4 + (threadIdx.x >> 6);
    const int lane = threadIdx.x & 63;
    const int n0 = wave * SP_NODES;
    if (n0 >= N) return;
    const int n1 = min(n0 + SP_NODES, N);
    const unsigned int* fp = (const unsigned int*)feat;
    const float bias0 = b2[2 * lane];
    const float bias1 = b2[2 * lane + 1];
    int g = graph_id[n0];
    float p0s = 0.f, p1s = 0.f;
    for (int node = n0; node < n1; ++node) {
        int gi = graph_id[node];
        if (gi != g) {
            atomicAdd(&hg_sum[g * HID2 + 2 * lane], p0s);
            atomicAdd(&hg_sum[g * HID2 + 2 * lane + 1], p1s);
            p0s = p1s = 0.f;
            g = gi;
        }
        const int beg = row[node];
        const int end = row[node + 1];
        float a0 = 0.f, a1 = 0.f;
        int j = beg;
        for (; j + 4 <= end; j += 4) {
            int s0 = csr_src[j], s1 = csr_src[j + 1], s2 = csr_src[j + 2], s3 = csr_src[j + 3];
            unsigned int q0 = fp[(size_t)s0 * 64 + lane];
            unsigned int q1 = fp[(size_t)s1 * 64 + lane];
            unsigned int q2 = fp[(size_t)s2 * 64 + lane];
            unsigned int q3 = fp[(size_t)s3 * 64 + lane];
            float lo, hi;
            bf2_unpack(q0, lo, hi); a0 += lo; a1 += hi;
            bf2_unpack(q1, lo, hi); a0 += lo; a1 += hi;
            bf2_unpack(q2, lo, hi); a0 += lo; a1 += hi;
            bf2_unpack(q3, lo, hi); a0 += lo; a1 += hi;
        }
        for (; j < end; ++j) {
            unsigned int q0 = fp[(size_t)csr_src[j] * 64 + lane];
            float lo, hi;
            bf2_unpack(q0, lo, hi); a0 += lo; a1 += hi;
        }
        float ii = inv_i[node];
        p0s += fmaxf(a0 * ii + bias0, 0.f);
        p1s += fmaxf(a1 * ii + bias1, 0.f);
    }
    atomicAdd(&hg_sum[g * HID2 + 2 * lane], p0s);
    atomicAdd(&hg_sum[g * HID2 + 2 * lane + 1], p1s);
}

// ---------------------------------------------------------------- MFMA bf16 GEMM
#define GBM 128
#define GBN 128
#define GBK 32
#define LPAD 40
typedef __attribute__((ext_vector_type(4))) float floatx4;
typedef __attribute__((ext_vector_type(8))) short shortx8;

__global__ __launch_bounds__(256) void mfma_gemm_kernel(const __hip_bfloat16* __restrict__ A,
                                                        const __hip_bfloat16* __restrict__ Bt,
                                                        __hip_bfloat16* __restrict__ C,
                                                        const float* __restrict__ scaleR,
                                                        const float* __restrict__ bias,
                                                        const float* __restrict__ scaleO,
                                                        int M, int Nn, int K, int doRelu) {
    __shared__ __align__(16) __hip_bfloat16 As[GBM * LPAD];
    __shared__ __align__(16) __hip_bfloat16 Bs[GBN * LPAD];
    const int tid = threadIdx.x;
    const int bm = blockIdx.x * GBM;
    const int bn = blockIdx.y * GBN;
    const int wid = tid >> 6;
    const int lane = tid & 63;
    const int wm = (wid & 1) * 64;
    const int wn = (wid >> 1) * 64;
    const int lrow = lane & 15;
    const int quad = lane >> 4;

    floatx4 acc[4][4] = {};

    for (int k0 = 0; k0 < K; k0 += GBK) {
#pragma unroll
        for (int it = 0; it < 2; ++it) {
            int slot = tid + (it << 8);
            int r = slot >> 2;
            int c = (slot & 3) << 3;
            int gr = bm + r;
            float4 v = make_float4(0.f, 0.f, 0.f, 0.f);
            if (gr < M) v = *reinterpret_cast<const float4*>(A + (size_t)gr * K + k0 + c);
            *reinterpret_cast<float4*>(&As[r * LPAD + c]) = v;
        }
#pragma unroll
        for (int it = 0; it < 2; ++it) {
            int slot = tid + (it << 8);
            int r = slot >> 2;
            int c = (slot & 3) << 3;
            float4 v = *reinterpret_cast<const float4*>(Bt + (size_t)(bn + r) * K + k0 + c);
            *reinterpret_cast<float4*>(&Bs[r * LPAD + c]) = v;
        }
        __syncthreads();

        shortx8 af[4], bf[4];
#pragma unroll
        for (int i = 0; i < 4; ++i)
            af[i] = *reinterpret_cast<const shortx8*>(&As[(wm + i * 16 + lrow) * LPAD + quad * 8]);
#pragma unroll
        for (int i = 0; i < 4; ++i)
            bf[i] = *reinterpret_cast<const shortx8*>(&Bs[(wn + i * 16 + lrow) * LPAD + quad * 8]);
#pragma unroll
        for (int im = 0; im < 4; ++im)
#pragma unroll
            for (int in = 0; in < 4; ++in)
                acc[im][in] = __builtin_amdgcn_mfma_f32_16x16x32_bf16(af[im], bf[in], acc[im][in], 0, 0, 0);
        __syncthreads();
    }

    float bv[4];
#pragma unroll
    for (int in = 0; in < 4; ++in)
        bv[in] = bias ? bias[bn + wn + in * 16 + lrow] : 0.f;

#pragma unroll
    for (int im = 0; im < 4; ++im) {
#pragma unroll
        for (int reg = 0; reg < 4; ++reg) {
            int r = bm + wm + im * 16 + quad * 4 + reg;
            if (r >= M) continue;
            float sR = scaleR ? scaleR[r] : 1.f;
            float sO = scaleO ? scaleO[r] : 1.f;
#pragma unroll
            for (int in = 0; in < 4; ++in) {
                int c = bn + wn + in * 16 + lrow;
                float v = acc[im][in][reg] * sR + bv[in];
                if (doRelu) v = fmaxf(v, 0.f);
                v *= sO;
                C[(size_t)r * Nn + c] = __float2bfloat16(v);
            }
        }
    }
}

// ---------------------------------------------------------------- tiny 3-layer MLP, block/graph
__device__ __forceinline__ int lower_bound_i(const int* a, int n, int key) {
    int lo = 0, hi = n;
    while (lo < hi) {
        int mid = (lo + hi) >> 1;
        if (a[mid] < key) lo = mid + 1; else hi = mid;
    }
    return lo;
}

__global__ __launch_bounds__(64) void mlp_kernel(const float* __restrict__ hg_sum,
                                                 const int* __restrict__ graph_id, int n,
                                                 const float* __restrict__ Wc1, const float* __restrict__ bc1,
                                                 const float* __restrict__ Wc2, const float* __restrict__ bc2,
                                                 const float* __restrict__ Wc3, const float* __restrict__ bc3,
                                                 float* __restrict__ out) {
    const int g = blockIdx.x;
    const int t = threadIdx.x;
    __shared__ float h[HID2];
    __shared__ float t1[12];
    __shared__ float t2[12];
    __shared__ float s_inv_cnt;
    if (t == 0) {
        int beg = lower_bound_i(graph_id, n, g);
        int end = lower_bound_i(graph_id, n, g + 1);
        int c = end - beg;
        s_inv_cnt = 1.0f / (float)max(c, 1);
    }
    __syncthreads();
    const float ic = s_inv_cnt;
    for (int i = t; i < HID2; i += 64) h[i] = hg_sum[g * HID2 + i] * ic;
    __syncthreads();
    if (t < 12) {
        float a = bc1[t];
        for (int k = 0; k < HID2; ++k) a += h[k] * Wc1[k * 12 + t];
        t1[t] = a;
    }
    __syncthreads();
    if (t < 12) {
        float a = bc2[t];
        for (int k = 0; k < 12; ++k) a += t1[k] * Wc2[k * 12 + t];
        t2[t] = a;
    }
    __syncthreads();
    if (t < 10) {
        float a = bc3[t];
        for (int k = 0; k < 12; ++k) a += t2[k] * Wc3[k * 10 + t];
        out[g * 10 + t] = a;
    }
}

// ================================================================ launch
extern "C" void kernel_launch(void* const* d_in, const int* in_sizes, int n_in,
                              void* d_out, int out_size, void* d_ws, size_t ws_size,
                              hipStream_t stream) {
    const float* x        = (const float*)d_in[0];
    const int*   src      = (const int*)d_in[1];
    const int*   dst      = (const int*)d_in[2];
    const int*   graph_id = (const int*)d_in[3];
    const float* W1       = (const float*)d_in[4];
    const float* b1       = (const float*)d_in[5];
    const float* W2       = (const float*)d_in[6];
    const float* b2       = (const float*)d_in[7];
    const float* Wc1      = (const float*)d_in[8];
    const float* bc1      = (const float*)d_in[9];
    const float* Wc2      = (const float*)d_in[10];
    const float* bc2      = (const float*)d_in[11];
    const float* Wc3      = (const float*)d_in[12];
    const float* bc3      = (const float*)d_in[13];
    float* out = (float*)d_out;

    const int N = in_sizes[0] / IN_DIM;   // 50000
    const int E = in_sizes[1];            // 800000
    const int G = out_size / 10;          // 64

    char* ws = (char*)d_ws;
    size_t off = 0;
    auto alloc = [&](size_t bytes) -> char* {
        char* p = ws + off;
        off = (off + bytes + 255) & ~(size_t)255;
        return p;
    };
    float* inv_i   = (float*)alloc((size_t)N * 4);
    float* inv_o   = (float*)alloc((size_t)N * 4);
    int*   row     = (int*)alloc((size_t)(N + 1) * 4);
    int*   ccnt    = (int*)alloc((size_t)NCHUNK * NBUCK * 4);
    int*   coffpre = (int*)alloc((size_t)NCHUNK * NBUCK * 4);
    int*   ctot    = (int*)alloc((size_t)NBUCK * 4);
    int2*  pairs   = (int2*)alloc((size_t)E * 8);
    int*   csr_src = (int*)alloc((size_t)E * 4);
    float* hg      = (float*)alloc((size_t)G * HID2 * 4);
    __hip_bfloat16* x_bf    = (__hip_bfloat16*)alloc((size_t)N * IN_DIM * 2);
    __hip_bfloat16* W1t     = (__hip_bfloat16*)alloc((size_t)IN_DIM * HID1 * 2);
    __hip_bfloat16* W2t     = (__hip_bfloat16*)alloc((size_t)HID1 * HID2 * 2);
    __hip_bfloat16* agg1_bf = (__hip_bfloat16*)alloc((size_t)N * IN_DIM * 2);
    __hip_bfloat16* h1_bf   = (__hip_bfloat16*)alloc((size_t)N * HID1 * 2);
    __hip_bfloat16* xw2_bf  = (__hip_bfloat16*)alloc((size_t)N * HID2 * 2);

    // src-histogram partials alias h1_bf (consumed by hist_src_reduce before gemm1 writes h1_bf)
    int* part = (int*)h1_bf;   // HB_CHUNKS * N ints = 12.8 MB <= 25.6 MB

    // deg_out -> inv_o (privatized, no global atomics); 64 chunks x 4 ranges = 256 blocks
    const int hchunk = (E + HB_CHUNKS - 1) / HB_CHUNKS;   // 12500 <= 65535 (16-bit counters)
    const int n_ranges = (N + HB_BINS - 1) / HB_BINS;     // 4
    hist_src<<<dim3(HB_CHUNKS, n_ranges), 256, 0, stream>>>(src, E, hchunk, part, N);
    hist_src_reduce<<<(N + 255) / 256, 256, 0, stream>>>(part, N, inv_o);

    // CSR build: coarse dst hist (+hg zero), per-bucket column scans, two-pass scatter.
    const int schunk = (E + NCHUNK - 1) / NCHUNK;
    coarse_hist<<<NCHUNK, 256, 0, stream>>>(dst, E, schunk, ccnt, hg, G * HID2);
    coarse_col<<<NBUCK, NCHUNK, 0, stream>>>(ccnt, coffpre, ctot);
    scat_a<<<NCHUNK, 256, 0, stream>>>(src, dst, E, schunk, coffpre, ctot, pairs);
    scat_b<<<NBUCK, 256, 0, stream>>>(pairs, ctot, N, row, inv_i, csr_src);

    // conversions: x*inv_o -> bf16, both weight transposes, one launch
    const int n4x = N * IN_DIM / 4;
    cvt_all<<<(n4x + IN_DIM * HID1 + HID1 * HID2 + 255) / 256, 256, 0, stream>>>(
        x, inv_o, x_bf, n4x, W1, W1t, W2, W2t);

    // Layer 1: agg1 = A * (x*inv_o); h1 = relu(inv_i*(agg1@W1) + b1) * inv_o
    spmm_kernel<<<(N + 3) / 4, 256, 0, stream>>>(x_bf, row, csr_src, agg1_bf, N);
    mfma_gemm_kernel<<<dim3((N + GBM - 1) / GBM, HID1 / GBN), 256, 0, stream>>>(
        agg1_bf, W1t, h1_bf, inv_i, b1, inv_o, N, HID1, IN_DIM, 1);

    // Layer 2: xw2 = h1 @ W2 (h1 carries inv_o); fused spmm+pool
    mfma_gemm_kernel<<<dim3((N + GBM - 1) / GBM, HID2 / GBN), 256, 0, stream>>>(
        h1_bf, W2t, xw2_bf, nullptr, nullptr, nullptr, N, HID2, HID1, 0);
    const int npw = (N + SP_NODES - 1) / SP_NODES;           // waves
    spmm_pool_kernel<<<(npw + 3) / 4, 256, 0, stream>>>(xw2_bf, row, csr_src, inv_i, b2,
                                                        graph_id, N, hg);

    // MLP (fused mean-divide)
    mlp_kernel<<<G, 64, 0, stream>>>(hg, graph_id, N, Wc1, bc1, Wc2, bc2, Wc3, bc3, out);
}